// Round 14
// baseline (174.125 us; speedup 1.0000x reference)
//
#include <hip/hip_runtime.h>
#include <hip/hip_fp16.h>

#define N_NODES 100000
#define N_EDGES 3200000
#define F_IN    128
#define DIM     16

#define SUP_SH  9
#define NSUP    196                      // ceil(100000/512)
#define SCAP    17920                    // per-super capacity: mean 16384 + 12 sigma
#define CHA     4096
#define NBLKA   ((N_EDGES + CHA - 1) / CHA)   // 782
#define NCAP    96                       // per-node csr capacity (mean 32 + 11 sigma)

static inline size_t alignup(size_t x) { return (x + 255) & ~(size_t)255; }

// ---------------------------------------------------------------------------
// zero-init of partA's relative cursors (256 ints; 1 block)
// ---------------------------------------------------------------------------
__global__ void zero_init(int* __restrict__ cursorA) {
    cursorA[threadIdx.x] = 0;
}

// ---------------------------------------------------------------------------
// pass A: partition edges into 196 super-buckets (512 nodes each).
// entry = src(17b) | node_local9 (bits 17..25).  LDS sort + u8 bucket tag.
// r13's register-held edges (8/thread, loaded once as 4x int4 -> pipelined,
// keeps VGPR pressure up) COMBINED with r12's single-wave shfl scan
// (4 buckets/lane on wave 0) -> 4 barriers/block instead of ~36.
// ---------------------------------------------------------------------------
__global__ __launch_bounds__(512) void partA(const int* __restrict__ row,
                                             const int* __restrict__ col,
                                             int* __restrict__ cursorA,
                                             unsigned* __restrict__ stageA) {
    __shared__ int hist[256], lstart[256], lcur[256], gbase[256];
    __shared__ unsigned stg[CHA];            // 16 KB
    __shared__ unsigned char stgb[CHA];      // 4 KB
    const int t = threadIdx.x;
    const int e0 = blockIdx.x * CHA;
    const int nv = min(CHA, N_EDGES - e0);
    const int i0 = t * 8;
    const bool act = (i0 < nv);              // nv is always a multiple of 8

    if (t < 256) hist[t] = 0;

    int4 c0, c1, r0, r1;
    if (act) {                               // load 8 edges once, keep in regs
        c0 = *(const int4*)(col + e0 + i0);
        c1 = *(const int4*)(col + e0 + i0 + 4);
        r0 = *(const int4*)(row + e0 + i0);
        r1 = *(const int4*)(row + e0 + i0 + 4);
    }
    __syncthreads();                                         // B1
    if (act) {
        atomicAdd(&hist[(unsigned)c0.x >> SUP_SH], 1);
        atomicAdd(&hist[(unsigned)c0.y >> SUP_SH], 1);
        atomicAdd(&hist[(unsigned)c0.z >> SUP_SH], 1);
        atomicAdd(&hist[(unsigned)c0.w >> SUP_SH], 1);
        atomicAdd(&hist[(unsigned)c1.x >> SUP_SH], 1);
        atomicAdd(&hist[(unsigned)c1.y >> SUP_SH], 1);
        atomicAdd(&hist[(unsigned)c1.z >> SUP_SH], 1);
        atomicAdd(&hist[(unsigned)c1.w >> SUP_SH], 1);
    }
    __syncthreads();                                         // B2
    if (t < 64) {                            // single-wave scan + reserve
        const int4 h4 = *(const int4*)&hist[t * 4];
        const int s = h4.x + h4.y + h4.z + h4.w;
        int incl = s;
#pragma unroll
        for (int d = 1; d < 64; d <<= 1) {
            int u = __shfl_up(incl, d, 64);
            if (t >= d) incl += u;
        }
        int ex = incl - s;
        int e0q[4] = { ex, ex + h4.x, ex + h4.x + h4.y, ex + h4.x + h4.y + h4.z };
        int hq[4]  = { h4.x, h4.y, h4.z, h4.w };
#pragma unroll
        for (int q = 0; q < 4; ++q) {
            int bkt = t * 4 + q;
            lstart[bkt] = e0q[q];
            lcur[bkt]   = e0q[q];
            if (hq[q]) {
                int gb = atomicAdd(&cursorA[bkt], hq[q]);    // relative
                if (gb + hq[q] > SCAP) gb = SCAP - hq[q];    // safety clamp
                gbase[bkt] = bkt * SCAP + gb;
            }
        }
    }
    __syncthreads();                                         // B3
    if (act) {
        int cc[8] = { c0.x, c0.y, c0.z, c0.w, c1.x, c1.y, c1.z, c1.w };
        int rr[8] = { r0.x, r0.y, r0.z, r0.w, r1.x, r1.y, r1.z, r1.w };
#pragma unroll
        for (int q = 0; q < 8; ++q) {
            int sp = (unsigned)cc[q] >> SUP_SH;
            int p = atomicAdd(&lcur[sp], 1);
            stg[p] = (unsigned)rr[q] | ((unsigned)(cc[q] & 511) << 17);
            stgb[p] = (unsigned char)sp;
        }
    }
    __syncthreads();                                         // B4
    for (int i = t; i < nv; i += 512) {                      // coalesced flush
        int sp = stgb[i];
        stageA[gbase[sp] + (i - lstart[sp])] = stg[i];
    }
}

// ---------------------------------------------------------------------------
// pass B: permute-scatter, ONE 1024-thread block per super. lcur[n] starts at
// the node's fixed region base; atomicAdd hands out slots; degree = final
// cursor - base (plain store).
// ---------------------------------------------------------------------------
__global__ __launch_bounds__(1024) void partB(const unsigned* __restrict__ stageA,
                                              const int* __restrict__ cursorA,
                                              int* __restrict__ nodeCur,
                                              unsigned* __restrict__ csr) {
    __shared__ int lcur[512];
    const int t = threadIdx.x;
    const int sup = blockIdx.x;
    const int nbase = sup << SUP_SH;
    if (t < 512) lcur[t] = (nbase + t) * NCAP;
    __syncthreads();
    const int base = sup * SCAP;
    const int cnt = min(cursorA[sup], SCAP);
    for (int i = t; i < cnt; i += 1024) {
        unsigned v = stageA[base + i];
        int n = (v >> 17) & 511;
        int pos = atomicAdd(&lcur[n], 1);
        if (pos < (nbase + n) * NCAP + NCAP)                 // safety clamp
            csr[pos] = v & 0x1FFFFu;
    }
    __syncthreads();
    if (t < 512) {
        int node = nbase + t;
        if (node < N_NODES) nodeCur[node] = min(lcur[t] - node * NCAP, NCAP);
    }
}

// ---------------------------------------------------------------------------
// GEMM1 + dinv fold, fp16 out: hd[N,16] = (half) rsqrt(deg+1)*(x @ W1)
// ---------------------------------------------------------------------------
__global__ __launch_bounds__(256) void gemm1(const float* __restrict__ x,
                                             const float* __restrict__ W,
                                             const int* __restrict__ nodeCur,
                                             __half* __restrict__ hd) {
    __shared__ float4 sW4[F_IN * DIM / 4];
    __shared__ float4 sX4[16][F_IN / 4 + 1];
    const int t = threadIdx.x;
#pragma unroll
    for (int i = t; i < F_IN * DIM / 4; i += 256) sW4[i] = ((const float4*)W)[i];
    const int base = blockIdx.x * 16;
#pragma unroll
    for (int i = t; i < 16 * (F_IN / 4); i += 256) {
        int r = i >> 5, k4 = i & 31;
        sX4[r][k4] = ((const float4*)(x + (size_t)(base + r) * F_IN))[k4];
    }
    __syncthreads();
    const float* sW = (const float*)sW4;
    const int rrow = t >> 4, cj = t & 15;
    const float* xr = (const float*)&sX4[rrow][0];
    float acc = 0.f;
#pragma unroll
    for (int k = 0; k < F_IN; ++k) acc += xr[k] * sW[k * DIM + cj];
    const float dc = rsqrtf((float)nodeCur[base + rrow] + 1.0f);
    hd[(size_t)(base + rrow) * DIM + cj] = __float2half(acc * dc);
}

// ---------------------------------------------------------------------------
// Aggregates: 8 lanes per node (lane f owns feature-pair f) -> no cross-lane
// reduce. uint4 csr loads; 8-edge unroll = 2 dwordx4 + 8 gathers in flight.
// ---------------------------------------------------------------------------
__device__ __forceinline__ void node_gather(const unsigned* __restrict__ csr,
                                            const __half2* __restrict__ h2,
                                            int p, int end, int f,
                                            float& ax, float& ay) {
    for (; p + 7 < end; p += 8) {
        uint4 ea = *(const uint4*)(csr + p);
        uint4 eb = *(const uint4*)(csr + p + 4);
        float2 v0 = __half22float2(h2[(size_t)ea.x * 8 + f]);
        float2 v1 = __half22float2(h2[(size_t)ea.y * 8 + f]);
        float2 v2 = __half22float2(h2[(size_t)ea.z * 8 + f]);
        float2 v3 = __half22float2(h2[(size_t)ea.w * 8 + f]);
        float2 v4 = __half22float2(h2[(size_t)eb.x * 8 + f]);
        float2 v5 = __half22float2(h2[(size_t)eb.y * 8 + f]);
        float2 v6 = __half22float2(h2[(size_t)eb.z * 8 + f]);
        float2 v7 = __half22float2(h2[(size_t)eb.w * 8 + f]);
        ax += ((v0.x + v1.x) + (v2.x + v3.x)) + ((v4.x + v5.x) + (v6.x + v7.x));
        ay += ((v0.y + v1.y) + (v2.y + v3.y)) + ((v4.y + v5.y) + (v6.y + v7.y));
    }
    if (p + 3 < end) {
        uint4 e4 = *(const uint4*)(csr + p);
        float2 v0 = __half22float2(h2[(size_t)e4.x * 8 + f]);
        float2 v1 = __half22float2(h2[(size_t)e4.y * 8 + f]);
        float2 v2 = __half22float2(h2[(size_t)e4.z * 8 + f]);
        float2 v3 = __half22float2(h2[(size_t)e4.w * 8 + f]);
        ax += (v0.x + v1.x) + (v2.x + v3.x);
        ay += (v0.y + v1.y) + (v2.y + v3.y);
        p += 4;
    }
    for (; p < end; ++p) {
        float2 v = __half22float2(h2[(size_t)csr[p] * 8 + f]);
        ax += v.x; ay += v.y;
    }
}

// layer 1: l1 = relu(dinv*(sum + hd[c]) + b1); fused GEMM2 via group shfl
__global__ __launch_bounds__(256) void agg1(const unsigned* __restrict__ csr,
                                            const int* __restrict__ nodeCur,
                                            const __half2* __restrict__ hd,
                                            const float* __restrict__ b1,
                                            const float* __restrict__ W2,
                                            __half2* __restrict__ hd2) {
    __shared__ float sW2[DIM * DIM];
    __shared__ float sb1[DIM];
    const int t = threadIdx.x;
    sW2[t] = W2[t];
    if (t < DIM) sb1[t] = b1[t];
    __syncthreads();
    const int lane = t & 63, f = lane & 7;
    const int node = blockIdx.x * 32 + ((t >> 6) << 3) + (lane >> 3);  // grid exact
    const int degv = nodeCur[node];
    const float dc = rsqrtf((float)degv + 1.0f);
    const int p0 = node * NCAP;
    float ax = 0.f, ay = 0.f;
    node_gather(csr, hd, p0, p0 + degv, f, ax, ay);
    float2 sv = __half22float2(hd[(size_t)node * 8 + f]);
    float fx = dc * (ax + sv.x) + sb1[2 * f];
    float fy = dc * (ay + sv.y) + sb1[2 * f + 1];
    fx = fmaxf(fx, 0.f); fy = fmaxf(fy, 0.f);
    float sx = 0.f, sy = 0.f;
    const int gl = lane & 56;                 // group base lane
#pragma unroll
    for (int mq = 0; mq < 8; ++mq) {
        float lo = __shfl(fx, gl + mq, 64);   // l1[2mq]
        float hi = __shfl(fy, gl + mq, 64);   // l1[2mq+1]
        sx += lo * sW2[(2 * mq) * DIM + 2 * f]     + hi * sW2[(2 * mq + 1) * DIM + 2 * f];
        sy += lo * sW2[(2 * mq) * DIM + 2 * f + 1] + hi * sW2[(2 * mq + 1) * DIM + 2 * f + 1];
    }
    hd2[(size_t)node * 8 + f] = __floats2half2_rn(dc * sx, dc * sy);
}

// layer 2: out = relu(dinv*(sum + hd2[c]) + b2)   (fp32 out)
__global__ __launch_bounds__(256) void agg2(const unsigned* __restrict__ csr,
                                            const int* __restrict__ nodeCur,
                                            const __half2* __restrict__ hd2,
                                            const float* __restrict__ b2,
                                            float2* __restrict__ out2) {
    __shared__ float sb2[DIM];
    const int t = threadIdx.x;
    if (t < DIM) sb2[t] = b2[t];
    __syncthreads();
    const int lane = t & 63, f = lane & 7;
    const int node = blockIdx.x * 32 + ((t >> 6) << 3) + (lane >> 3);
    const int degv = nodeCur[node];
    const float dc = rsqrtf((float)degv + 1.0f);
    const int p0 = node * NCAP;
    float ax = 0.f, ay = 0.f;
    node_gather(csr, hd2, p0, p0 + degv, f, ax, ay);
    float2 sv = __half22float2(hd2[(size_t)node * 8 + f]);
    float fx = dc * (ax + sv.x) + sb2[2 * f];
    float fy = dc * (ay + sv.y) + sb2[2 * f + 1];
    out2[(size_t)node * 8 + f] = make_float2(fmaxf(fx, 0.f), fmaxf(fy, 0.f));
}

extern "C" void kernel_launch(void* const* d_in, const int* in_sizes, int n_in,
                              void* d_out, int out_size, void* d_ws, size_t ws_size,
                              hipStream_t stream) {
    const float* x   = (const float*)d_in[0];
    const int*   ei  = (const int*)d_in[1];        // [2, E] flat: row then col
    const float* W1  = (const float*)d_in[2];
    const float* b1  = (const float*)d_in[3];
    const float* W2  = (const float*)d_in[4];
    const float* b2  = (const float*)d_in[5];
    float*       out = (float*)d_out;

    const int* row = ei;
    const int* col = ei + N_EDGES;

    // workspace (~53.5 MB of ~268 MB; stageA reused as hd/hd2 after partB)
    char* ws = (char*)d_ws;
    size_t o = 0;
    auto take = [&](size_t bytes) { char* p = ws + o; o = alignup(o + bytes); return p; };
    int*      nodeCur = (int*)     take((size_t)N_NODES * 4);         // degrees
    int*      cursorA = (int*)     take((size_t)256 * 4);             // rel cursors
    unsigned* stageA  = (unsigned*)take((size_t)NSUP * SCAP * 4);     // 14.0 MB
    unsigned* csr     = (unsigned*)take((size_t)N_NODES * NCAP * 4);  // 38.4 MB

    __half* hd  = (__half*)stageA;                                    // after partB
    __half* hd2 = (__half*)((char*)stageA + alignup((size_t)N_NODES * DIM * 2));

    // graph preprocessing: 2-pass radix to per-node (padded) CSR
    zero_init<<<1, 256, 0, stream>>>(cursorA);
    partA<<<NBLKA, 512, 0, stream>>>(row, col, cursorA, stageA);
    partB<<<NSUP, 1024, 0, stream>>>(stageA, cursorA, nodeCur, csr);

    // network
    gemm1<<<N_NODES / 16, 256, 0, stream>>>(x, W1, nodeCur, hd);
    agg1<<<N_NODES / 32, 256, 0, stream>>>(csr, nodeCur, (const __half2*)hd,
                                           b1, W2, (__half2*)hd2);
    agg2<<<N_NODES / 32, 256, 0, stream>>>(csr, nodeCur, (const __half2*)hd2,
                                           b2, (float2*)out);
}

// Round 15
// 128.065 us; speedup vs baseline: 1.3597x; 1.3597x over previous
//
#include <hip/hip_runtime.h>
#include <hip/hip_fp16.h>

#define N_NODES 100000
#define N_EDGES 3200000
#define F_IN    128
#define DIM     16

#define SUP_SH  9
#define NSUP    196                      // ceil(100000/512)
#define SCAP    17920                    // per-super capacity: mean 16384 + 12 sigma
#define CHA     4096
#define NBLKA   ((N_EDGES + CHA - 1) / CHA)   // 782
#define NCAP    96                       // per-node csr capacity (mean 32 + 11 sigma)

static inline size_t alignup(size_t x) { return (x + 255) & ~(size_t)255; }

// ---------------------------------------------------------------------------
// zero-init of partA's relative cursors (256 ints; 1 block)
// ---------------------------------------------------------------------------
__global__ void zero_init(int* __restrict__ cursorA) {
    cursorA[threadIdx.x] = 0;
}

// ---------------------------------------------------------------------------
// pass A (r13 verbatim — do not touch): edges held in registers (8/thread,
// 4x int4 loaded once) + LADDER scan. The shfl-scan variant collapses VGPR
// to 8-16 and de-pipelines all loads (r12: 75us, r14: 70us vs this: ~29us).
// ---------------------------------------------------------------------------
__global__ __launch_bounds__(512) void partA(const int* __restrict__ row,
                                             const int* __restrict__ col,
                                             int* __restrict__ cursorA,
                                             unsigned* __restrict__ stageA) {
    __shared__ int hist[256], lstart[256], lcur[256], gbase[256], scanT[256];
    __shared__ unsigned stg[CHA];            // 16 KB
    __shared__ unsigned char stgb[CHA];      // 4 KB
    const int t = threadIdx.x;
    const int e0 = blockIdx.x * CHA;
    const int nv = min(CHA, N_EDGES - e0);
    const int i0 = t * 8;
    const bool act = (i0 < nv);              // nv is always a multiple of 8

    if (t < 256) hist[t] = 0;

    int4 c0, c1, r0, r1;
    if (act) {                               // load 8 edges once
        c0 = *(const int4*)(col + e0 + i0);
        c1 = *(const int4*)(col + e0 + i0 + 4);
        r0 = *(const int4*)(row + e0 + i0);
        r1 = *(const int4*)(row + e0 + i0 + 4);
    }
    __syncthreads();                                         // B1
    if (act) {
        atomicAdd(&hist[(unsigned)c0.x >> SUP_SH], 1);
        atomicAdd(&hist[(unsigned)c0.y >> SUP_SH], 1);
        atomicAdd(&hist[(unsigned)c0.z >> SUP_SH], 1);
        atomicAdd(&hist[(unsigned)c0.w >> SUP_SH], 1);
        atomicAdd(&hist[(unsigned)c1.x >> SUP_SH], 1);
        atomicAdd(&hist[(unsigned)c1.y >> SUP_SH], 1);
        atomicAdd(&hist[(unsigned)c1.z >> SUP_SH], 1);
        atomicAdd(&hist[(unsigned)c1.w >> SUP_SH], 1);
    }
    __syncthreads();                                         // B2
    int v = 0;
    if (t < 256) { v = hist[t]; scanT[t] = v; }
    __syncthreads();
#pragma unroll
    for (int off = 1; off < 256; off <<= 1) {                // proven ladder
        int a = (t >= off && t < 256) ? scanT[t - off] : 0;
        __syncthreads();
        if (t < 256) scanT[t] += a;
        __syncthreads();
    }
    if (t < 256) {
        int ex = scanT[t] - v;
        lstart[t] = ex; lcur[t] = ex;
        if (v) {
            int gb = atomicAdd(&cursorA[t], v);              // relative
            if (gb + v > SCAP) gb = SCAP - v;                // safety clamp
            gbase[t] = t * SCAP + gb;
        }
    }
    __syncthreads();                                         // B3
    if (act) {
        int cc[8] = { c0.x, c0.y, c0.z, c0.w, c1.x, c1.y, c1.z, c1.w };
        int rr[8] = { r0.x, r0.y, r0.z, r0.w, r1.x, r1.y, r1.z, r1.w };
#pragma unroll
        for (int q = 0; q < 8; ++q) {
            int sp = (unsigned)cc[q] >> SUP_SH;
            int p = atomicAdd(&lcur[sp], 1);
            stg[p] = (unsigned)rr[q] | ((unsigned)(cc[q] & 511) << 17);
            stgb[p] = (unsigned char)sp;
        }
    }
    __syncthreads();                                         // B4
    for (int i = t; i < nv; i += 512) {                      // coalesced flush
        int sp = stgb[i];
        stageA[gbase[sp] + (i - lstart[sp])] = stg[i];
    }
}

// ---------------------------------------------------------------------------
// pass B: permute-scatter, ONE 1024-thread block per super. lcur[n] starts at
// the node's fixed region base; atomicAdd hands out slots; degree = final
// cursor - base (plain store). csr entries are PRE-SCALED (src*8 = half2
// index) so the aggs skip one shift-add per gather.
// ---------------------------------------------------------------------------
__global__ __launch_bounds__(1024) void partB(const unsigned* __restrict__ stageA,
                                              const int* __restrict__ cursorA,
                                              int* __restrict__ nodeCur,
                                              unsigned* __restrict__ csr) {
    __shared__ int lcur[512];
    const int t = threadIdx.x;
    const int sup = blockIdx.x;
    const int nbase = sup << SUP_SH;
    if (t < 512) lcur[t] = (nbase + t) * NCAP;
    __syncthreads();
    const int base = sup * SCAP;
    const int cnt = min(cursorA[sup], SCAP);
    for (int i = t; i < cnt; i += 1024) {
        unsigned v = stageA[base + i];
        int n = (v >> 17) & 511;
        int pos = atomicAdd(&lcur[n], 1);
        if (pos < (nbase + n) * NCAP + NCAP)                 // safety clamp
            csr[pos] = (v & 0x1FFFFu) << 3;  // pre-scaled half2 index
    }
    __syncthreads();
    if (t < 512) {
        int node = nbase + t;
        if (node < N_NODES) nodeCur[node] = min(lcur[t] - node * NCAP, NCAP);
    }
}

// ---------------------------------------------------------------------------
// GEMM1 + dinv fold, fp16 out: hd[N,16] = (half) rsqrt(deg+1)*(x @ W1)
// ---------------------------------------------------------------------------
__global__ __launch_bounds__(256) void gemm1(const float* __restrict__ x,
                                             const float* __restrict__ W,
                                             const int* __restrict__ nodeCur,
                                             __half* __restrict__ hd) {
    __shared__ float4 sW4[F_IN * DIM / 4];
    __shared__ float4 sX4[16][F_IN / 4 + 1];
    const int t = threadIdx.x;
#pragma unroll
    for (int i = t; i < F_IN * DIM / 4; i += 256) sW4[i] = ((const float4*)W)[i];
    const int base = blockIdx.x * 16;
#pragma unroll
    for (int i = t; i < 16 * (F_IN / 4); i += 256) {
        int r = i >> 5, k4 = i & 31;
        sX4[r][k4] = ((const float4*)(x + (size_t)(base + r) * F_IN))[k4];
    }
    __syncthreads();
    const float* sW = (const float*)sW4;
    const int rrow = t >> 4, cj = t & 15;
    const float* xr = (const float*)&sX4[rrow][0];
    float acc = 0.f;
#pragma unroll
    for (int k = 0; k < F_IN; ++k) acc += xr[k] * sW[k * DIM + cj];
    const float dc = rsqrtf((float)nodeCur[base + rrow] + 1.0f);
    hd[(size_t)(base + rrow) * DIM + cj] = __float2half(acc * dc);
}

// ---------------------------------------------------------------------------
// Aggregates: 8 lanes per node (lane f owns feature-pair f) -> no cross-lane
// reduce. csr holds PRE-SCALED half2 indices (src*8). 16-edge-deep first
// stage: 4 dwordx4 + 16 gathers in flight per lane-group -> half the serial
// iterations at avg degree 32.
// ---------------------------------------------------------------------------
__device__ __forceinline__ void node_gather(const unsigned* __restrict__ csr,
                                            const __half2* __restrict__ h2,
                                            int p, int end, int f,
                                            float& ax, float& ay) {
    for (; p + 15 < end; p += 16) {
        uint4 ea = *(const uint4*)(csr + p);
        uint4 eb = *(const uint4*)(csr + p + 4);
        uint4 ec = *(const uint4*)(csr + p + 8);
        uint4 ed = *(const uint4*)(csr + p + 12);
        float2 v0 = __half22float2(h2[ea.x + f]);
        float2 v1 = __half22float2(h2[ea.y + f]);
        float2 v2 = __half22float2(h2[ea.z + f]);
        float2 v3 = __half22float2(h2[ea.w + f]);
        float2 v4 = __half22float2(h2[eb.x + f]);
        float2 v5 = __half22float2(h2[eb.y + f]);
        float2 v6 = __half22float2(h2[eb.z + f]);
        float2 v7 = __half22float2(h2[eb.w + f]);
        float2 v8 = __half22float2(h2[ec.x + f]);
        float2 v9 = __half22float2(h2[ec.y + f]);
        float2 va = __half22float2(h2[ec.z + f]);
        float2 vb = __half22float2(h2[ec.w + f]);
        float2 vc = __half22float2(h2[ed.x + f]);
        float2 vd = __half22float2(h2[ed.y + f]);
        float2 ve = __half22float2(h2[ed.z + f]);
        float2 vf = __half22float2(h2[ed.w + f]);
        ax += (((v0.x + v1.x) + (v2.x + v3.x)) + ((v4.x + v5.x) + (v6.x + v7.x)))
            + (((v8.x + v9.x) + (va.x + vb.x)) + ((vc.x + vd.x) + (ve.x + vf.x)));
        ay += (((v0.y + v1.y) + (v2.y + v3.y)) + ((v4.y + v5.y) + (v6.y + v7.y)))
            + (((v8.y + v9.y) + (va.y + vb.y)) + ((vc.y + vd.y) + (ve.y + vf.y)));
    }
    if (p + 7 < end) {
        uint4 ea = *(const uint4*)(csr + p);
        uint4 eb = *(const uint4*)(csr + p + 4);
        float2 v0 = __half22float2(h2[ea.x + f]);
        float2 v1 = __half22float2(h2[ea.y + f]);
        float2 v2 = __half22float2(h2[ea.z + f]);
        float2 v3 = __half22float2(h2[ea.w + f]);
        float2 v4 = __half22float2(h2[eb.x + f]);
        float2 v5 = __half22float2(h2[eb.y + f]);
        float2 v6 = __half22float2(h2[eb.z + f]);
        float2 v7 = __half22float2(h2[eb.w + f]);
        ax += ((v0.x + v1.x) + (v2.x + v3.x)) + ((v4.x + v5.x) + (v6.x + v7.x));
        ay += ((v0.y + v1.y) + (v2.y + v3.y)) + ((v4.y + v5.y) + (v6.y + v7.y));
        p += 8;
    }
    if (p + 3 < end) {
        uint4 e4 = *(const uint4*)(csr + p);
        float2 v0 = __half22float2(h2[e4.x + f]);
        float2 v1 = __half22float2(h2[e4.y + f]);
        float2 v2 = __half22float2(h2[e4.z + f]);
        float2 v3 = __half22float2(h2[e4.w + f]);
        ax += (v0.x + v1.x) + (v2.x + v3.x);
        ay += (v0.y + v1.y) + (v2.y + v3.y);
        p += 4;
    }
    for (; p < end; ++p) {
        float2 v = __half22float2(h2[csr[p] + f]);
        ax += v.x; ay += v.y;
    }
}

// layer 1: l1 = relu(dinv*(sum + hd[c]) + b1); fused GEMM2 via group shfl
__global__ __launch_bounds__(256) void agg1(const unsigned* __restrict__ csr,
                                            const int* __restrict__ nodeCur,
                                            const __half2* __restrict__ hd,
                                            const float* __restrict__ b1,
                                            const float* __restrict__ W2,
                                            __half2* __restrict__ hd2) {
    __shared__ float sW2[DIM * DIM];
    __shared__ float sb1[DIM];
    const int t = threadIdx.x;
    sW2[t] = W2[t];
    if (t < DIM) sb1[t] = b1[t];
    __syncthreads();
    const int lane = t & 63, f = lane & 7;
    const int node = blockIdx.x * 32 + ((t >> 6) << 3) + (lane >> 3);  // grid exact
    const int degv = nodeCur[node];
    const float dc = rsqrtf((float)degv + 1.0f);
    const int p0 = node * NCAP;
    float ax = 0.f, ay = 0.f;
    node_gather(csr, hd, p0, p0 + degv, f, ax, ay);
    float2 sv = __half22float2(hd[(size_t)node * 8 + f]);
    float fx = dc * (ax + sv.x) + sb1[2 * f];
    float fy = dc * (ay + sv.y) + sb1[2 * f + 1];
    fx = fmaxf(fx, 0.f); fy = fmaxf(fy, 0.f);
    float sx = 0.f, sy = 0.f;
    const int gl = lane & 56;                 // group base lane
#pragma unroll
    for (int mq = 0; mq < 8; ++mq) {
        float lo = __shfl(fx, gl + mq, 64);   // l1[2mq]
        float hi = __shfl(fy, gl + mq, 64);   // l1[2mq+1]
        sx += lo * sW2[(2 * mq) * DIM + 2 * f]     + hi * sW2[(2 * mq + 1) * DIM + 2 * f];
        sy += lo * sW2[(2 * mq) * DIM + 2 * f + 1] + hi * sW2[(2 * mq + 1) * DIM + 2 * f + 1];
    }
    hd2[(size_t)node * 8 + f] = __floats2half2_rn(dc * sx, dc * sy);
}

// layer 2: out = relu(dinv*(sum + hd2[c]) + b2)   (fp32 out)
__global__ __launch_bounds__(256) void agg2(const unsigned* __restrict__ csr,
                                            const int* __restrict__ nodeCur,
                                            const __half2* __restrict__ hd2,
                                            const float* __restrict__ b2,
                                            float2* __restrict__ out2) {
    __shared__ float sb2[DIM];
    const int t = threadIdx.x;
    if (t < DIM) sb2[t] = b2[t];
    __syncthreads();
    const int lane = t & 63, f = lane & 7;
    const int node = blockIdx.x * 32 + ((t >> 6) << 3) + (lane >> 3);
    const int degv = nodeCur[node];
    const float dc = rsqrtf((float)degv + 1.0f);
    const int p0 = node * NCAP;
    float ax = 0.f, ay = 0.f;
    node_gather(csr, hd2, p0, p0 + degv, f, ax, ay);
    float2 sv = __half22float2(hd2[(size_t)node * 8 + f]);
    float fx = dc * (ax + sv.x) + sb2[2 * f];
    float fy = dc * (ay + sv.y) + sb2[2 * f + 1];
    out2[(size_t)node * 8 + f] = make_float2(fmaxf(fx, 0.f), fmaxf(fy, 0.f));
}

extern "C" void kernel_launch(void* const* d_in, const int* in_sizes, int n_in,
                              void* d_out, int out_size, void* d_ws, size_t ws_size,
                              hipStream_t stream) {
    const float* x   = (const float*)d_in[0];
    const int*   ei  = (const int*)d_in[1];        // [2, E] flat: row then col
    const float* W1  = (const float*)d_in[2];
    const float* b1  = (const float*)d_in[3];
    const float* W2  = (const float*)d_in[4];
    const float* b2  = (const float*)d_in[5];
    float*       out = (float*)d_out;

    const int* row = ei;
    const int* col = ei + N_EDGES;

    // workspace (~53.5 MB of ~268 MB; stageA reused as hd/hd2 after partB)
    char* ws = (char*)d_ws;
    size_t o = 0;
    auto take = [&](size_t bytes) { char* p = ws + o; o = alignup(o + bytes); return p; };
    int*      nodeCur = (int*)     take((size_t)N_NODES * 4);         // degrees
    int*      cursorA = (int*)     take((size_t)256 * 4);             // rel cursors
    unsigned* stageA  = (unsigned*)take((size_t)NSUP * SCAP * 4);     // 14.0 MB
    unsigned* csr     = (unsigned*)take((size_t)N_NODES * NCAP * 4);  // 38.4 MB

    __half* hd  = (__half*)stageA;                                    // after partB
    __half* hd2 = (__half*)((char*)stageA + alignup((size_t)N_NODES * DIM * 2));

    // graph preprocessing: 2-pass radix to per-node (padded) CSR
    zero_init<<<1, 256, 0, stream>>>(cursorA);
    partA<<<NBLKA, 512, 0, stream>>>(row, col, cursorA, stageA);
    partB<<<NSUP, 1024, 0, stream>>>(stageA, cursorA, nodeCur, csr);

    // network
    gemm1<<<N_NODES / 16, 256, 0, stream>>>(x, W1, nodeCur, hd);
    agg1<<<N_NODES / 32, 256, 0, stream>>>(csr, nodeCur, (const __half2*)hd,
                                           b1, W2, (__half2*)hd2);
    agg2<<<N_NODES / 32, 256, 0, stream>>>(csr, nodeCur, (const __half2*)hd2,
                                           b2, (float2*)out);
}

// Round 16
// 121.425 us; speedup vs baseline: 1.4340x; 1.0547x over previous
//
#include <hip/hip_runtime.h>
#include <hip/hip_fp16.h>

#define N_NODES 100000
#define N_EDGES 3200000
#define F_IN    128
#define DIM     16

#define SUP_SH  9
#define NSUP    196                      // ceil(100000/512)
#define SCAP    17920                    // per-super capacity: mean 16384 + 12 sigma
#define CHA     4096
#define NBLKA   ((N_EDGES + CHA - 1) / CHA)   // 782
#define NCAP    96                       // per-node csr capacity (mean 32 + 11 sigma)
#define GROWS   32                       // gemm rows per block (512 thr)
#define NBLKG   (N_NODES / GROWS)        // 3125

static inline size_t alignup(size_t x) { return (x + 255) & ~(size_t)255; }

// ---------------------------------------------------------------------------
// zero-init of partA's relative cursors (256 ints; 1 block)
// ---------------------------------------------------------------------------
__global__ void zero_init(int* __restrict__ cursorA) {
    cursorA[threadIdx.x] = 0;
}

// ---------------------------------------------------------------------------
// FUSED partition + GEMM1: grid = NBLKA partition blocks + NBLKG gemm blocks.
// partA path (r13 verbatim — do not touch: edges in registers + LADDER scan;
// shfl-scan collapses VGPR and de-pipelines, r12/r14 proved 2.4x slower) is
// barrier/latency-bound with idle VALU+HBM; gemm blocks backfill those pipes.
// gemm path writes UNFOLDED hu = x@W1 (dinv folded later by partB epilogue).
// LDS: single 25.6KB char array, carved per path.
// ---------------------------------------------------------------------------
__global__ __launch_bounds__(512) void partA_gemm(const int* __restrict__ row,
                                                  const int* __restrict__ col,
                                                  int* __restrict__ cursorA,
                                                  unsigned* __restrict__ stageA,
                                                  const float* __restrict__ x,
                                                  const float* __restrict__ W,
                                                  __half* __restrict__ hu) {
    __shared__ __align__(16) char smem[25600];
    const int t = threadIdx.x;

    if (blockIdx.x < NBLKA) {
        // ---------------- partition path ----------------
        int* hist   = (int*)smem;                 // 256
        int* lstart = hist + 256;
        int* lcur   = hist + 512;
        int* gbase  = hist + 768;
        int* scanT  = hist + 1024;
        unsigned* stg = (unsigned*)(smem + 5120);          // 16 KB
        unsigned char* stgb = (unsigned char*)(smem + 21504); // 4 KB

        const int e0 = blockIdx.x * CHA;
        const int nv = min(CHA, N_EDGES - e0);
        const int i0 = t * 8;
        const bool act = (i0 < nv);          // nv is always a multiple of 8

        if (t < 256) hist[t] = 0;

        int4 c0, c1, r0, r1;
        if (act) {                           // load 8 edges once, keep in regs
            c0 = *(const int4*)(col + e0 + i0);
            c1 = *(const int4*)(col + e0 + i0 + 4);
            r0 = *(const int4*)(row + e0 + i0);
            r1 = *(const int4*)(row + e0 + i0 + 4);
        }
        __syncthreads();                                     // B1
        if (act) {
            atomicAdd(&hist[(unsigned)c0.x >> SUP_SH], 1);
            atomicAdd(&hist[(unsigned)c0.y >> SUP_SH], 1);
            atomicAdd(&hist[(unsigned)c0.z >> SUP_SH], 1);
            atomicAdd(&hist[(unsigned)c0.w >> SUP_SH], 1);
            atomicAdd(&hist[(unsigned)c1.x >> SUP_SH], 1);
            atomicAdd(&hist[(unsigned)c1.y >> SUP_SH], 1);
            atomicAdd(&hist[(unsigned)c1.z >> SUP_SH], 1);
            atomicAdd(&hist[(unsigned)c1.w >> SUP_SH], 1);
        }
        __syncthreads();                                     // B2
        int v = 0;
        if (t < 256) { v = hist[t]; scanT[t] = v; }
        __syncthreads();
#pragma unroll
        for (int off = 1; off < 256; off <<= 1) {            // proven ladder
            int a = (t >= off && t < 256) ? scanT[t - off] : 0;
            __syncthreads();
            if (t < 256) scanT[t] += a;
            __syncthreads();
        }
        if (t < 256) {
            int ex = scanT[t] - v;
            lstart[t] = ex; lcur[t] = ex;
            if (v) {
                int gb = atomicAdd(&cursorA[t], v);          // relative
                if (gb + v > SCAP) gb = SCAP - v;            // safety clamp
                gbase[t] = t * SCAP + gb;
            }
        }
        __syncthreads();                                     // B3
        if (act) {
            int cc[8] = { c0.x, c0.y, c0.z, c0.w, c1.x, c1.y, c1.z, c1.w };
            int rr[8] = { r0.x, r0.y, r0.z, r0.w, r1.x, r1.y, r1.z, r1.w };
#pragma unroll
            for (int q = 0; q < 8; ++q) {
                int sp = (unsigned)cc[q] >> SUP_SH;
                int p = atomicAdd(&lcur[sp], 1);
                stg[p] = (unsigned)rr[q] | ((unsigned)(cc[q] & 511) << 17);
                stgb[p] = (unsigned char)sp;
            }
        }
        __syncthreads();                                     // B4
        for (int i = t; i < nv; i += 512) {                  // coalesced flush
            int sp = stgb[i];
            stageA[gbase[sp] + (i - lstart[sp])] = stg[i];
        }
    } else {
        // ---------------- gemm path: hu = x @ W1 (unfolded fp16) ----------
        float4* sW4 = (float4*)smem;                         // 8 KB
        float4 (*sX4)[F_IN / 4 + 1] = (float4 (*)[F_IN / 4 + 1])(smem + 8192); // 16.9 KB
        const int gb = blockIdx.x - NBLKA;
        const int base = gb * GROWS;
        sW4[t] = ((const float4*)W)[t];       // 512 float4 = whole W1
#pragma unroll
        for (int i = t; i < GROWS * (F_IN / 4); i += 512) {
            int r = i >> 5, k4 = i & 31;
            sX4[r][k4] = ((const float4*)(x + (size_t)(base + r) * F_IN))[k4];
        }
        __syncthreads();
        const float* sW = (const float*)sW4;
        const int rrow = t >> 4, cj = t & 15;
        const float* xr = (const float*)&sX4[rrow][0];
        float acc = 0.f;
#pragma unroll
        for (int k = 0; k < F_IN; ++k) acc += xr[k] * sW[k * DIM + cj];
        hu[(size_t)(base + rrow) * DIM + cj] = __float2half(acc);
    }
}

// ---------------------------------------------------------------------------
// pass B: permute-scatter + dinv-fold epilogue. ONE 1024-thread block per
// super. csr entries PRE-SCALED (src*8 = half2 index). Epilogue scales
// hu -> hd with dinv computed from the final cursors (degrees).
// ---------------------------------------------------------------------------
__global__ __launch_bounds__(1024) void partB(const unsigned* __restrict__ stageA,
                                              const int* __restrict__ cursorA,
                                              int* __restrict__ nodeCur,
                                              unsigned* __restrict__ csr,
                                              const __half2* __restrict__ hu,
                                              __half2* __restrict__ hd) {
    __shared__ int lcur[512];
    __shared__ float dl[512];
    const int t = threadIdx.x;
    const int sup = blockIdx.x;
    const int nbase = sup << SUP_SH;
    if (t < 512) lcur[t] = (nbase + t) * NCAP;
    __syncthreads();
    const int base = sup * SCAP;
    const int cnt = min(cursorA[sup], SCAP);
    for (int i = t; i < cnt; i += 1024) {
        unsigned v = stageA[base + i];
        int n = (v >> 17) & 511;
        int pos = atomicAdd(&lcur[n], 1);
        if (pos < (nbase + n) * NCAP + NCAP)                 // safety clamp
            csr[pos] = (v & 0x1FFFFu) << 3;  // pre-scaled half2 index
    }
    __syncthreads();
    if (t < 512) {
        int node = nbase + t;
        if (node < N_NODES) {
            int deg = min(lcur[t] - node * NCAP, NCAP);
            nodeCur[node] = deg;
            dl[t] = rsqrtf((float)deg + 1.0f);
        }
    }
    __syncthreads();
    const int nn = min(N_NODES - nbase, 512);
    for (int idx = t; idx < nn * 8; idx += 1024) {           // hd = dinv * hu
        int nl = idx >> 3, f = idx & 7;
        float2 vf = __half22float2(hu[(size_t)(nbase + nl) * 8 + f]);
        float d = dl[nl];
        hd[(size_t)(nbase + nl) * 8 + f] = __floats2half2_rn(vf.x * d, vf.y * d);
    }
}

// ---------------------------------------------------------------------------
// Aggregates: 8 lanes per node (lane f owns feature-pair f) -> no cross-lane
// reduce. csr holds PRE-SCALED half2 indices (src*8). 16-edge-deep first
// stage: 4 dwordx4 + 16 gathers in flight per lane-group.
// ---------------------------------------------------------------------------
__device__ __forceinline__ void node_gather(const unsigned* __restrict__ csr,
                                            const __half2* __restrict__ h2,
                                            int p, int end, int f,
                                            float& ax, float& ay) {
    for (; p + 15 < end; p += 16) {
        uint4 ea = *(const uint4*)(csr + p);
        uint4 eb = *(const uint4*)(csr + p + 4);
        uint4 ec = *(const uint4*)(csr + p + 8);
        uint4 ed = *(const uint4*)(csr + p + 12);
        float2 v0 = __half22float2(h2[ea.x + f]);
        float2 v1 = __half22float2(h2[ea.y + f]);
        float2 v2 = __half22float2(h2[ea.z + f]);
        float2 v3 = __half22float2(h2[ea.w + f]);
        float2 v4 = __half22float2(h2[eb.x + f]);
        float2 v5 = __half22float2(h2[eb.y + f]);
        float2 v6 = __half22float2(h2[eb.z + f]);
        float2 v7 = __half22float2(h2[eb.w + f]);
        float2 v8 = __half22float2(h2[ec.x + f]);
        float2 v9 = __half22float2(h2[ec.y + f]);
        float2 va = __half22float2(h2[ec.z + f]);
        float2 vb = __half22float2(h2[ec.w + f]);
        float2 vc = __half22float2(h2[ed.x + f]);
        float2 vd = __half22float2(h2[ed.y + f]);
        float2 ve = __half22float2(h2[ed.z + f]);
        float2 vf = __half22float2(h2[ed.w + f]);
        ax += (((v0.x + v1.x) + (v2.x + v3.x)) + ((v4.x + v5.x) + (v6.x + v7.x)))
            + (((v8.x + v9.x) + (va.x + vb.x)) + ((vc.x + vd.x) + (ve.x + vf.x)));
        ay += (((v0.y + v1.y) + (v2.y + v3.y)) + ((v4.y + v5.y) + (v6.y + v7.y)))
            + (((v8.y + v9.y) + (va.y + vb.y)) + ((vc.y + vd.y) + (ve.y + vf.y)));
    }
    if (p + 7 < end) {
        uint4 ea = *(const uint4*)(csr + p);
        uint4 eb = *(const uint4*)(csr + p + 4);
        float2 v0 = __half22float2(h2[ea.x + f]);
        float2 v1 = __half22float2(h2[ea.y + f]);
        float2 v2 = __half22float2(h2[ea.z + f]);
        float2 v3 = __half22float2(h2[ea.w + f]);
        float2 v4 = __half22float2(h2[eb.x + f]);
        float2 v5 = __half22float2(h2[eb.y + f]);
        float2 v6 = __half22float2(h2[eb.z + f]);
        float2 v7 = __half22float2(h2[eb.w + f]);
        ax += ((v0.x + v1.x) + (v2.x + v3.x)) + ((v4.x + v5.x) + (v6.x + v7.x));
        ay += ((v0.y + v1.y) + (v2.y + v3.y)) + ((v4.y + v5.y) + (v6.y + v7.y));
        p += 8;
    }
    if (p + 3 < end) {
        uint4 e4 = *(const uint4*)(csr + p);
        float2 v0 = __half22float2(h2[e4.x + f]);
        float2 v1 = __half22float2(h2[e4.y + f]);
        float2 v2 = __half22float2(h2[e4.z + f]);
        float2 v3 = __half22float2(h2[e4.w + f]);
        ax += (v0.x + v1.x) + (v2.x + v3.x);
        ay += (v0.y + v1.y) + (v2.y + v3.y);
        p += 4;
    }
    for (; p < end; ++p) {
        float2 v = __half22float2(h2[csr[p] + f]);
        ax += v.x; ay += v.y;
    }
}

// layer 1: l1 = relu(dinv*(sum + hd[c]) + b1); fused GEMM2 via group shfl
__global__ __launch_bounds__(256) void agg1(const unsigned* __restrict__ csr,
                                            const int* __restrict__ nodeCur,
                                            const __half2* __restrict__ hd,
                                            const float* __restrict__ b1,
                                            const float* __restrict__ W2,
                                            __half2* __restrict__ hd2) {
    __shared__ float sW2[DIM * DIM];
    __shared__ float sb1[DIM];
    const int t = threadIdx.x;
    sW2[t] = W2[t];
    if (t < DIM) sb1[t] = b1[t];
    __syncthreads();
    const int lane = t & 63, f = lane & 7;
    const int node = blockIdx.x * 32 + ((t >> 6) << 3) + (lane >> 3);  // grid exact
    const int degv = nodeCur[node];
    const float dc = rsqrtf((float)degv + 1.0f);
    const int p0 = node * NCAP;
    float ax = 0.f, ay = 0.f;
    node_gather(csr, hd, p0, p0 + degv, f, ax, ay);
    float2 sv = __half22float2(hd[(size_t)node * 8 + f]);
    float fx = dc * (ax + sv.x) + sb1[2 * f];
    float fy = dc * (ay + sv.y) + sb1[2 * f + 1];
    fx = fmaxf(fx, 0.f); fy = fmaxf(fy, 0.f);
    float sx = 0.f, sy = 0.f;
    const int gl = lane & 56;                 // group base lane
#pragma unroll
    for (int mq = 0; mq < 8; ++mq) {
        float lo = __shfl(fx, gl + mq, 64);   // l1[2mq]
        float hi = __shfl(fy, gl + mq, 64);   // l1[2mq+1]
        sx += lo * sW2[(2 * mq) * DIM + 2 * f]     + hi * sW2[(2 * mq + 1) * DIM + 2 * f];
        sy += lo * sW2[(2 * mq) * DIM + 2 * f + 1] + hi * sW2[(2 * mq + 1) * DIM + 2 * f + 1];
    }
    hd2[(size_t)node * 8 + f] = __floats2half2_rn(dc * sx, dc * sy);
}

// layer 2: out = relu(dinv*(sum + hd2[c]) + b2)   (fp32 out)
__global__ __launch_bounds__(256) void agg2(const unsigned* __restrict__ csr,
                                            const int* __restrict__ nodeCur,
                                            const __half2* __restrict__ hd2,
                                            const float* __restrict__ b2,
                                            float2* __restrict__ out2) {
    __shared__ float sb2[DIM];
    const int t = threadIdx.x;
    if (t < DIM) sb2[t] = b2[t];
    __syncthreads();
    const int lane = t & 63, f = lane & 7;
    const int node = blockIdx.x * 32 + ((t >> 6) << 3) + (lane >> 3);
    const int degv = nodeCur[node];
    const float dc = rsqrtf((float)degv + 1.0f);
    const int p0 = node * NCAP;
    float ax = 0.f, ay = 0.f;
    node_gather(csr, hd2, p0, p0 + degv, f, ax, ay);
    float2 sv = __half22float2(hd2[(size_t)node * 8 + f]);
    float fx = dc * (ax + sv.x) + sb2[2 * f];
    float fy = dc * (ay + sv.y) + sb2[2 * f + 1];
    out2[(size_t)node * 8 + f] = make_float2(fmaxf(fx, 0.f), fmaxf(fy, 0.f));
}

extern "C" void kernel_launch(void* const* d_in, const int* in_sizes, int n_in,
                              void* d_out, int out_size, void* d_ws, size_t ws_size,
                              hipStream_t stream) {
    const float* x   = (const float*)d_in[0];
    const int*   ei  = (const int*)d_in[1];        // [2, E] flat: row then col
    const float* W1  = (const float*)d_in[2];
    const float* b1  = (const float*)d_in[3];
    const float* W2  = (const float*)d_in[4];
    const float* b2  = (const float*)d_in[5];
    float*       out = (float*)d_out;

    const int* row = ei;
    const int* col = ei + N_EDGES;

    // workspace (~63 MB of ~268 MB; hu/hd/hd2 now dedicated — stageA is live
    // during the fused kernel)
    char* ws = (char*)d_ws;
    size_t o = 0;
    auto take = [&](size_t bytes) { char* p = ws + o; o = alignup(o + bytes); return p; };
    int*      nodeCur = (int*)     take((size_t)N_NODES * 4);         // degrees
    int*      cursorA = (int*)     take((size_t)256 * 4);             // rel cursors
    unsigned* stageA  = (unsigned*)take((size_t)NSUP * SCAP * 4);     // 14.0 MB
    unsigned* csr     = (unsigned*)take((size_t)N_NODES * NCAP * 4);  // 38.4 MB
    __half*   hu      = (__half*)  take((size_t)N_NODES * DIM * 2);   // 3.2 MB
    __half*   hd      = (__half*)  take((size_t)N_NODES * DIM * 2);   // 3.2 MB
    __half*   hd2     = (__half*)  take((size_t)N_NODES * DIM * 2);   // 3.2 MB

    // preprocessing + GEMM1 co-scheduled in one kernel
    zero_init<<<1, 256, 0, stream>>>(cursorA);
    partA_gemm<<<NBLKA + NBLKG, 512, 0, stream>>>(row, col, cursorA, stageA,
                                                  x, W1, hu);
    partB<<<NSUP, 1024, 0, stream>>>(stageA, cursorA, nodeCur, csr,
                                     (const __half2*)hu, (__half2*)hd);

    // network
    agg1<<<N_NODES / 32, 256, 0, stream>>>(csr, nodeCur, (const __half2*)hd,
                                           b1, W2, (__half2*)hd2);
    agg2<<<N_NODES / 32, 256, 0, stream>>>(csr, nodeCur, (const __half2*)hd2,
                                           b2, (float2*)out);
}

// Round 17
// 110.500 us; speedup vs baseline: 1.5758x; 1.0989x over previous
//
#include <hip/hip_runtime.h>
#include <hip/hip_fp16.h>

#define N_NODES 100000
#define N_EDGES 3200000
#define F_IN    128
#define DIM     16

#define SUP_SH  9
#define NSUP    196                      // ceil(100000/512)
#define SCAP    17920                    // per-super capacity: mean 16384 + 12 sigma
#define CHA     4096
#define NBLKA   ((N_EDGES + CHA - 1) / CHA)   // 782
#define NCAP    96                       // per-node csr capacity (mean 32 + 11 sigma)
#define GROWS   32                       // gemm rows per block (512 thr)
#define NBLKG   (N_NODES / GROWS)        // 3125

static inline size_t alignup(size_t x) { return (x + 255) & ~(size_t)255; }

// ---------------------------------------------------------------------------
// zero-init of partA's relative cursors (256 ints; 1 block)
// ---------------------------------------------------------------------------
__global__ void zero_init(int* __restrict__ cursorA) {
    cursorA[threadIdx.x] = 0;
}

// ---------------------------------------------------------------------------
// FUSED partition + GEMM1 with INTERLEAVED block ids: bid%5==0 -> partition
// (782 of 3907), else gemm (3125). r16 proved back-to-back ordering gives
// ZERO overlap (fused dur == serial sum): partition blocks dispatch first and
// monopolize CUs. Interleaving co-locates barrier-bound partition waves with
// VALU-bound gemm waves on every CU from t=0.
// partA path internals r13-verbatim (shfl-scan collapses codegen, r12/r14).
// ---------------------------------------------------------------------------
__global__ __launch_bounds__(512) void partA_gemm(const int* __restrict__ row,
                                                  const int* __restrict__ col,
                                                  int* __restrict__ cursorA,
                                                  unsigned* __restrict__ stageA,
                                                  const float* __restrict__ x,
                                                  const float* __restrict__ W,
                                                  __half* __restrict__ hu) {
    __shared__ __align__(16) char smem[25600];
    const int t = threadIdx.x;
    const int bid = blockIdx.x;

    if (bid % 5 == 0) {
        // ---------------- partition path (block bid/5 of 782) ----------------
        int* hist   = (int*)smem;                 // 256
        int* lstart = hist + 256;
        int* lcur   = hist + 512;
        int* gbase  = hist + 768;
        int* scanT  = hist + 1024;
        unsigned* stg = (unsigned*)(smem + 5120);             // 16 KB
        unsigned char* stgb = (unsigned char*)(smem + 21504); // 4 KB

        const int e0 = (bid / 5) * CHA;
        const int nv = min(CHA, N_EDGES - e0);
        const int i0 = t * 8;
        const bool act = (i0 < nv);          // nv is always a multiple of 8

        if (t < 256) hist[t] = 0;

        int4 c0, c1, r0, r1;
        if (act) {                           // load 8 edges once, keep in regs
            c0 = *(const int4*)(col + e0 + i0);
            c1 = *(const int4*)(col + e0 + i0 + 4);
            r0 = *(const int4*)(row + e0 + i0);
            r1 = *(const int4*)(row + e0 + i0 + 4);
        }
        __syncthreads();                                     // B1
        if (act) {
            atomicAdd(&hist[(unsigned)c0.x >> SUP_SH], 1);
            atomicAdd(&hist[(unsigned)c0.y >> SUP_SH], 1);
            atomicAdd(&hist[(unsigned)c0.z >> SUP_SH], 1);
            atomicAdd(&hist[(unsigned)c0.w >> SUP_SH], 1);
            atomicAdd(&hist[(unsigned)c1.x >> SUP_SH], 1);
            atomicAdd(&hist[(unsigned)c1.y >> SUP_SH], 1);
            atomicAdd(&hist[(unsigned)c1.z >> SUP_SH], 1);
            atomicAdd(&hist[(unsigned)c1.w >> SUP_SH], 1);
        }
        __syncthreads();                                     // B2
        int v = 0;
        if (t < 256) { v = hist[t]; scanT[t] = v; }
        __syncthreads();
#pragma unroll
        for (int off = 1; off < 256; off <<= 1) {            // proven ladder
            int a = (t >= off && t < 256) ? scanT[t - off] : 0;
            __syncthreads();
            if (t < 256) scanT[t] += a;
            __syncthreads();
        }
        if (t < 256) {
            int ex = scanT[t] - v;
            lstart[t] = ex; lcur[t] = ex;
            if (v) {
                int gb = atomicAdd(&cursorA[t], v);          // relative
                if (gb + v > SCAP) gb = SCAP - v;            // safety clamp
                gbase[t] = t * SCAP + gb;
            }
        }
        __syncthreads();                                     // B3
        if (act) {
            int cc[8] = { c0.x, c0.y, c0.z, c0.w, c1.x, c1.y, c1.z, c1.w };
            int rr[8] = { r0.x, r0.y, r0.z, r0.w, r1.x, r1.y, r1.z, r1.w };
#pragma unroll
            for (int q = 0; q < 8; ++q) {
                int sp = (unsigned)cc[q] >> SUP_SH;
                int p = atomicAdd(&lcur[sp], 1);
                stg[p] = (unsigned)rr[q] | ((unsigned)(cc[q] & 511) << 17);
                stgb[p] = (unsigned char)sp;
            }
        }
        __syncthreads();                                     // B4
        for (int i = t; i < nv; i += 512) {                  // coalesced flush
            int sp = stgb[i];
            stageA[gbase[sp] + (i - lstart[sp])] = stg[i];
        }
    } else {
        // ---------------- gemm path: hu = x @ W1 (unfolded fp16) ----------
        float4* sW4 = (float4*)smem;                         // 8 KB
        float4 (*sX4)[F_IN / 4 + 1] = (float4 (*)[F_IN / 4 + 1])(smem + 8192); // 16.9 KB
        const int gb = bid - bid / 5 - 1;     // gemm block index (0..3124)
        const int base = gb * GROWS;
        sW4[t] = ((const float4*)W)[t];       // 512 float4 = whole W1
#pragma unroll
        for (int i = t; i < GROWS * (F_IN / 4); i += 512) {
            int r = i >> 5, k4 = i & 31;
            sX4[r][k4] = ((const float4*)(x + (size_t)(base + r) * F_IN))[k4];
        }
        __syncthreads();
        const float* sW = (const float*)sW4;
        const int rrow = t >> 4, cj = t & 15;
        const float* xr = (const float*)&sX4[rrow][0];
        float acc = 0.f;
#pragma unroll
        for (int k = 0; k < F_IN; ++k) acc += xr[k] * sW[k * DIM + cj];
        hu[(size_t)(base + rrow) * DIM + cj] = __float2half(acc);
    }
}

// ---------------------------------------------------------------------------
// pass B: permute-scatter + dinv-fold epilogue. ONE 1024-thread block per
// super. csr entries PRE-SCALED (src*8 = half2 index). Epilogue scales
// hu -> hd with dinv computed from the final cursors (degrees).
// ---------------------------------------------------------------------------
__global__ __launch_bounds__(1024) void partB(const unsigned* __restrict__ stageA,
                                              const int* __restrict__ cursorA,
                                              int* __restrict__ nodeCur,
                                              unsigned* __restrict__ csr,
                                              const __half2* __restrict__ hu,
                                              __half2* __restrict__ hd) {
    __shared__ int lcur[512];
    __shared__ float dl[512];
    const int t = threadIdx.x;
    const int sup = blockIdx.x;
    const int nbase = sup << SUP_SH;
    if (t < 512) lcur[t] = (nbase + t) * NCAP;
    __syncthreads();
    const int base = sup * SCAP;
    const int cnt = min(cursorA[sup], SCAP);
    for (int i = t; i < cnt; i += 1024) {
        unsigned v = stageA[base + i];
        int n = (v >> 17) & 511;
        int pos = atomicAdd(&lcur[n], 1);
        if (pos < (nbase + n) * NCAP + NCAP)                 // safety clamp
            csr[pos] = (v & 0x1FFFFu) << 3;  // pre-scaled half2 index
    }
    __syncthreads();
    if (t < 512) {
        int node = nbase + t;
        if (node < N_NODES) {
            int deg = min(lcur[t] - node * NCAP, NCAP);
            nodeCur[node] = deg;
            dl[t] = rsqrtf((float)deg + 1.0f);
        }
    }
    __syncthreads();
    const int nn = min(N_NODES - nbase, 512);
    for (int idx = t; idx < nn * 8; idx += 1024) {           // hd = dinv * hu
        int nl = idx >> 3, f = idx & 7;
        float2 vf = __half22float2(hu[(size_t)(nbase + nl) * 8 + f]);
        float d = dl[nl];
        hd[(size_t)(nbase + nl) * 8 + f] = __floats2half2_rn(vf.x * d, vf.y * d);
    }
}

// ---------------------------------------------------------------------------
// Aggregates: 8 lanes per node (lane f owns feature-pair f) -> no cross-lane
// reduce. csr holds PRE-SCALED half2 indices (src*8). 16-edge-deep first
// stage: 4 dwordx4 + 16 gathers in flight per lane-group.
// ---------------------------------------------------------------------------
__device__ __forceinline__ void node_gather(const unsigned* __restrict__ csr,
                                            const __half2* __restrict__ h2,
                                            int p, int end, int f,
                                            float& ax, float& ay) {
    for (; p + 15 < end; p += 16) {
        uint4 ea = *(const uint4*)(csr + p);
        uint4 eb = *(const uint4*)(csr + p + 4);
        uint4 ec = *(const uint4*)(csr + p + 8);
        uint4 ed = *(const uint4*)(csr + p + 12);
        float2 v0 = __half22float2(h2[ea.x + f]);
        float2 v1 = __half22float2(h2[ea.y + f]);
        float2 v2 = __half22float2(h2[ea.z + f]);
        float2 v3 = __half22float2(h2[ea.w + f]);
        float2 v4 = __half22float2(h2[eb.x + f]);
        float2 v5 = __half22float2(h2[eb.y + f]);
        float2 v6 = __half22float2(h2[eb.z + f]);
        float2 v7 = __half22float2(h2[eb.w + f]);
        float2 v8 = __half22float2(h2[ec.x + f]);
        float2 v9 = __half22float2(h2[ec.y + f]);
        float2 va = __half22float2(h2[ec.z + f]);
        float2 vb = __half22float2(h2[ec.w + f]);
        float2 vc = __half22float2(h2[ed.x + f]);
        float2 vd = __half22float2(h2[ed.y + f]);
        float2 ve = __half22float2(h2[ed.z + f]);
        float2 vf = __half22float2(h2[ed.w + f]);
        ax += (((v0.x + v1.x) + (v2.x + v3.x)) + ((v4.x + v5.x) + (v6.x + v7.x)))
            + (((v8.x + v9.x) + (va.x + vb.x)) + ((vc.x + vd.x) + (ve.x + vf.x)));
        ay += (((v0.y + v1.y) + (v2.y + v3.y)) + ((v4.y + v5.y) + (v6.y + v7.y)))
            + (((v8.y + v9.y) + (va.y + vb.y)) + ((vc.y + vd.y) + (ve.y + vf.y)));
    }
    if (p + 7 < end) {
        uint4 ea = *(const uint4*)(csr + p);
        uint4 eb = *(const uint4*)(csr + p + 4);
        float2 v0 = __half22float2(h2[ea.x + f]);
        float2 v1 = __half22float2(h2[ea.y + f]);
        float2 v2 = __half22float2(h2[ea.z + f]);
        float2 v3 = __half22float2(h2[ea.w + f]);
        float2 v4 = __half22float2(h2[eb.x + f]);
        float2 v5 = __half22float2(h2[eb.y + f]);
        float2 v6 = __half22float2(h2[eb.z + f]);
        float2 v7 = __half22float2(h2[eb.w + f]);
        ax += ((v0.x + v1.x) + (v2.x + v3.x)) + ((v4.x + v5.x) + (v6.x + v7.x));
        ay += ((v0.y + v1.y) + (v2.y + v3.y)) + ((v4.y + v5.y) + (v6.y + v7.y));
        p += 8;
    }
    if (p + 3 < end) {
        uint4 e4 = *(const uint4*)(csr + p);
        float2 v0 = __half22float2(h2[e4.x + f]);
        float2 v1 = __half22float2(h2[e4.y + f]);
        float2 v2 = __half22float2(h2[e4.z + f]);
        float2 v3 = __half22float2(h2[e4.w + f]);
        ax += (v0.x + v1.x) + (v2.x + v3.x);
        ay += (v0.y + v1.y) + (v2.y + v3.y);
        p += 4;
    }
    for (; p < end; ++p) {
        float2 v = __half22float2(h2[csr[p] + f]);
        ax += v.x; ay += v.y;
    }
}

// layer 1: l1 = relu(dinv*(sum + hd[c]) + b1); fused GEMM2 via group shfl
__global__ __launch_bounds__(256) void agg1(const unsigned* __restrict__ csr,
                                            const int* __restrict__ nodeCur,
                                            const __half2* __restrict__ hd,
                                            const float* __restrict__ b1,
                                            const float* __restrict__ W2,
                                            __half2* __restrict__ hd2) {
    __shared__ float sW2[DIM * DIM];
    __shared__ float sb1[DIM];
    const int t = threadIdx.x;
    sW2[t] = W2[t];
    if (t < DIM) sb1[t] = b1[t];
    __syncthreads();
    const int lane = t & 63, f = lane & 7;
    const int node = blockIdx.x * 32 + ((t >> 6) << 3) + (lane >> 3);  // grid exact
    const int degv = nodeCur[node];
    const float dc = rsqrtf((float)degv + 1.0f);
    const int p0 = node * NCAP;
    float ax = 0.f, ay = 0.f;
    node_gather(csr, hd, p0, p0 + degv, f, ax, ay);
    float2 sv = __half22float2(hd[(size_t)node * 8 + f]);
    float fx = dc * (ax + sv.x) + sb1[2 * f];
    float fy = dc * (ay + sv.y) + sb1[2 * f + 1];
    fx = fmaxf(fx, 0.f); fy = fmaxf(fy, 0.f);
    float sx = 0.f, sy = 0.f;
    const int gl = lane & 56;                 // group base lane
#pragma unroll
    for (int mq = 0; mq < 8; ++mq) {
        float lo = __shfl(fx, gl + mq, 64);   // l1[2mq]
        float hi = __shfl(fy, gl + mq, 64);   // l1[2mq+1]
        sx += lo * sW2[(2 * mq) * DIM + 2 * f]     + hi * sW2[(2 * mq + 1) * DIM + 2 * f];
        sy += lo * sW2[(2 * mq) * DIM + 2 * f + 1] + hi * sW2[(2 * mq + 1) * DIM + 2 * f + 1];
    }
    hd2[(size_t)node * 8 + f] = __floats2half2_rn(dc * sx, dc * sy);
}

// layer 2: out = relu(dinv*(sum + hd2[c]) + b2)   (fp32 out)
__global__ __launch_bounds__(256) void agg2(const unsigned* __restrict__ csr,
                                            const int* __restrict__ nodeCur,
                                            const __half2* __restrict__ hd2,
                                            const float* __restrict__ b2,
                                            float2* __restrict__ out2) {
    __shared__ float sb2[DIM];
    const int t = threadIdx.x;
    if (t < DIM) sb2[t] = b2[t];
    __syncthreads();
    const int lane = t & 63, f = lane & 7;
    const int node = blockIdx.x * 32 + ((t >> 6) << 3) + (lane >> 3);
    const int degv = nodeCur[node];
    const float dc = rsqrtf((float)degv + 1.0f);
    const int p0 = node * NCAP;
    float ax = 0.f, ay = 0.f;
    node_gather(csr, hd2, p0, p0 + degv, f, ax, ay);
    float2 sv = __half22float2(hd2[(size_t)node * 8 + f]);
    float fx = dc * (ax + sv.x) + sb2[2 * f];
    float fy = dc * (ay + sv.y) + sb2[2 * f + 1];
    out2[(size_t)node * 8 + f] = make_float2(fmaxf(fx, 0.f), fmaxf(fy, 0.f));
}

extern "C" void kernel_launch(void* const* d_in, const int* in_sizes, int n_in,
                              void* d_out, int out_size, void* d_ws, size_t ws_size,
                              hipStream_t stream) {
    const float* x   = (const float*)d_in[0];
    const int*   ei  = (const int*)d_in[1];        // [2, E] flat: row then col
    const float* W1  = (const float*)d_in[2];
    const float* b1  = (const float*)d_in[3];
    const float* W2  = (const float*)d_in[4];
    const float* b2  = (const float*)d_in[5];
    float*       out = (float*)d_out;

    const int* row = ei;
    const int* col = ei + N_EDGES;

    // workspace (~63 MB of ~268 MB)
    char* ws = (char*)d_ws;
    size_t o = 0;
    auto take = [&](size_t bytes) { char* p = ws + o; o = alignup(o + bytes); return p; };
    int*      nodeCur = (int*)     take((size_t)N_NODES * 4);         // degrees
    int*      cursorA = (int*)     take((size_t)256 * 4);             // rel cursors
    unsigned* stageA  = (unsigned*)take((size_t)NSUP * SCAP * 4);     // 14.0 MB
    unsigned* csr     = (unsigned*)take((size_t)N_NODES * NCAP * 4);  // 38.4 MB
    __half*   hu      = (__half*)  take((size_t)N_NODES * DIM * 2);   // 3.2 MB
    __half*   hd      = (__half*)  take((size_t)N_NODES * DIM * 2);   // 3.2 MB
    __half*   hd2     = (__half*)  take((size_t)N_NODES * DIM * 2);   // 3.2 MB

    // preprocessing + GEMM1 co-scheduled (interleaved block ids)
    zero_init<<<1, 256, 0, stream>>>(cursorA);
    partA_gemm<<<NBLKA + NBLKG, 512, 0, stream>>>(row, col, cursorA, stageA,
                                                  x, W1, hu);
    partB<<<NSUP, 1024, 0, stream>>>(stageA, cursorA, nodeCur, csr,
                                     (const __half2*)hu, (__half2*)hd);

    // network
    agg1<<<N_NODES / 32, 256, 0, stream>>>(csr, nodeCur, (const __half2*)hd,
                                           b1, W2, (__half2*)hd2);
    agg2<<<N_NODES / 32, 256, 0, stream>>>(csr, nodeCur, (const __half2*)hd2,
                                           b2, (float2*)out);
}

// Round 18
// 110.457 us; speedup vs baseline: 1.5764x; 1.0004x over previous
//
#include <hip/hip_runtime.h>
#include <hip/hip_fp16.h>

#define N_NODES 100000
#define N_EDGES 3200000
#define F_IN    128
#define DIM     16

#define SUP_SH  9
#define NSUP    196                      // ceil(100000/512)
#define SCAP    17920                    // per-super capacity: mean 16384 + 12 sigma
#define CHA     4096
#define NBLKA   ((N_EDGES + CHA - 1) / CHA)   // 782
#define NCAP    96                       // per-node csr capacity (mean 32 + 11 sigma)
#define GROWS   32                       // gemm rows per block (512 thr)
#define NBLKG   (N_NODES / GROWS)        // 3125

static inline size_t alignup(size_t x) { return (x + 255) & ~(size_t)255; }

// ---------------------------------------------------------------------------
// zero-init of partA's relative cursors (256 ints; 1 block)
// ---------------------------------------------------------------------------
__global__ void zero_init(int* __restrict__ cursorA) {
    cursorA[threadIdx.x] = 0;
}

// ---------------------------------------------------------------------------
// FUSED partition + GEMM1 with INTERLEAVED block ids: bid%5==0 -> partition
// (782 of 3907), else gemm (3125). Interleave proven r17: +11us vs r16's
// back-to-back ordering. partA internals r13-verbatim (shfl-scan collapses
// codegen, r12/r14 — do not touch).
// ---------------------------------------------------------------------------
__global__ __launch_bounds__(512) void partA_gemm(const int* __restrict__ row,
                                                  const int* __restrict__ col,
                                                  int* __restrict__ cursorA,
                                                  unsigned* __restrict__ stageA,
                                                  const float* __restrict__ x,
                                                  const float* __restrict__ W,
                                                  __half* __restrict__ hu) {
    __shared__ __align__(16) char smem[25600];
    const int t = threadIdx.x;
    const int bid = blockIdx.x;

    if (bid % 5 == 0) {
        // ---------------- partition path (block bid/5 of 782) ----------------
        int* hist   = (int*)smem;                 // 256
        int* lstart = hist + 256;
        int* lcur   = hist + 512;
        int* gbase  = hist + 768;
        int* scanT  = hist + 1024;
        unsigned* stg = (unsigned*)(smem + 5120);             // 16 KB
        unsigned char* stgb = (unsigned char*)(smem + 21504); // 4 KB

        const int e0 = (bid / 5) * CHA;
        const int nv = min(CHA, N_EDGES - e0);
        const int i0 = t * 8;
        const bool act = (i0 < nv);          // nv is always a multiple of 8

        if (t < 256) hist[t] = 0;

        int4 c0, c1, r0, r1;
        if (act) {                           // load 8 edges once, keep in regs
            c0 = *(const int4*)(col + e0 + i0);
            c1 = *(const int4*)(col + e0 + i0 + 4);
            r0 = *(const int4*)(row + e0 + i0);
            r1 = *(const int4*)(row + e0 + i0 + 4);
        }
        __syncthreads();                                     // B1
        if (act) {
            atomicAdd(&hist[(unsigned)c0.x >> SUP_SH], 1);
            atomicAdd(&hist[(unsigned)c0.y >> SUP_SH], 1);
            atomicAdd(&hist[(unsigned)c0.z >> SUP_SH], 1);
            atomicAdd(&hist[(unsigned)c0.w >> SUP_SH], 1);
            atomicAdd(&hist[(unsigned)c1.x >> SUP_SH], 1);
            atomicAdd(&hist[(unsigned)c1.y >> SUP_SH], 1);
            atomicAdd(&hist[(unsigned)c1.z >> SUP_SH], 1);
            atomicAdd(&hist[(unsigned)c1.w >> SUP_SH], 1);
        }
        __syncthreads();                                     // B2
        int v = 0;
        if (t < 256) { v = hist[t]; scanT[t] = v; }
        __syncthreads();
#pragma unroll
        for (int off = 1; off < 256; off <<= 1) {            // proven ladder
            int a = (t >= off && t < 256) ? scanT[t - off] : 0;
            __syncthreads();
            if (t < 256) scanT[t] += a;
            __syncthreads();
        }
        if (t < 256) {
            int ex = scanT[t] - v;
            lstart[t] = ex; lcur[t] = ex;
            if (v) {
                int gb = atomicAdd(&cursorA[t], v);          // relative
                if (gb + v > SCAP) gb = SCAP - v;            // safety clamp
                gbase[t] = t * SCAP + gb;
            }
        }
        __syncthreads();                                     // B3
        if (act) {
            int cc[8] = { c0.x, c0.y, c0.z, c0.w, c1.x, c1.y, c1.z, c1.w };
            int rr[8] = { r0.x, r0.y, r0.z, r0.w, r1.x, r1.y, r1.z, r1.w };
#pragma unroll
            for (int q = 0; q < 8; ++q) {
                int sp = (unsigned)cc[q] >> SUP_SH;
                int p = atomicAdd(&lcur[sp], 1);
                stg[p] = (unsigned)rr[q] | ((unsigned)(cc[q] & 511) << 17);
                stgb[p] = (unsigned char)sp;
            }
        }
        __syncthreads();                                     // B4
        for (int i = t; i < nv; i += 512) {                  // coalesced flush
            int sp = stgb[i];
            stageA[gbase[sp] + (i - lstart[sp])] = stg[i];
        }
    } else {
        // ---------------- gemm path: hu = x @ W1 (unfolded fp16) ----------
        float4* sW4 = (float4*)smem;                         // 8 KB
        float4 (*sX4)[F_IN / 4 + 1] = (float4 (*)[F_IN / 4 + 1])(smem + 8192); // 16.9 KB
        const int gb = bid - bid / 5 - 1;     // gemm block index (0..3124)
        const int base = gb * GROWS;
        sW4[t] = ((const float4*)W)[t];       // 512 float4 = whole W1
#pragma unroll
        for (int i = t; i < GROWS * (F_IN / 4); i += 512) {
            int r = i >> 5, k4 = i & 31;
            sX4[r][k4] = ((const float4*)(x + (size_t)(base + r) * F_IN))[k4];
        }
        __syncthreads();
        const float* sW = (const float*)sW4;
        const int rrow = t >> 4, cj = t & 15;
        const float* xr = (const float*)&sX4[rrow][0];
        float acc = 0.f;
#pragma unroll
        for (int k = 0; k < F_IN; ++k) acc += xr[k] * sW[k * DIM + cj];
        hu[(size_t)(base + rrow) * DIM + cj] = __float2half(acc);
    }
}

// ---------------------------------------------------------------------------
// pass B: permute-scatter + dinv-fold epilogue. ONE 1024-thread block per
// super. csr entries PRE-SCALED (src*8 = half2 index). Epilogue scales
// hu -> hd with dinv computed from the final cursors (degrees).
// ---------------------------------------------------------------------------
__global__ __launch_bounds__(1024) void partB(const unsigned* __restrict__ stageA,
                                              const int* __restrict__ cursorA,
                                              int* __restrict__ nodeCur,
                                              unsigned* __restrict__ csr,
                                              const __half2* __restrict__ hu,
                                              __half2* __restrict__ hd) {
    __shared__ int lcur[512];
    __shared__ float dl[512];
    const int t = threadIdx.x;
    const int sup = blockIdx.x;
    const int nbase = sup << SUP_SH;
    if (t < 512) lcur[t] = (nbase + t) * NCAP;
    __syncthreads();
    const int base = sup * SCAP;
    const int cnt = min(cursorA[sup], SCAP);
    for (int i = t; i < cnt; i += 1024) {
        unsigned v = stageA[base + i];
        int n = (v >> 17) & 511;
        int pos = atomicAdd(&lcur[n], 1);
        if (pos < (nbase + n) * NCAP + NCAP)                 // safety clamp
            csr[pos] = (v & 0x1FFFFu) << 3;  // pre-scaled half2 index
    }
    __syncthreads();
    if (t < 512) {
        int node = nbase + t;
        if (node < N_NODES) {
            int deg = min(lcur[t] - node * NCAP, NCAP);
            nodeCur[node] = deg;
            dl[t] = rsqrtf((float)deg + 1.0f);
        }
    }
    __syncthreads();
    const int nn = min(N_NODES - nbase, 512);
    for (int idx = t; idx < nn * 8; idx += 1024) {           // hd = dinv * hu
        int nl = idx >> 3, f = idx & 7;
        float2 vf = __half22float2(hu[(size_t)(nbase + nl) * 8 + f]);
        float d = dl[nl];
        hd[(size_t)(nbase + nl) * 8 + f] = __floats2half2_rn(vf.x * d, vf.y * d);
    }
}

// ---------------------------------------------------------------------------
// Aggregates: 8 lanes per node, no cross-lane reduce. PAIRWISE PACKED fp16
// accumulation: adjacent gathers summed with one v_pk_add_f16 (__hadd2),
// converted per PAIR -> 40 VALU per 16 edges vs 64 (cvt+add halved).
// Error: <=0.5ulp per pair-add, x16 pairs x dinv(~0.17) ~ 7e-4/layer worst.
// ---------------------------------------------------------------------------
__device__ __forceinline__ void node_gather(const unsigned* __restrict__ csr,
                                            const __half2* __restrict__ h2,
                                            int p, int end, int f,
                                            float& ax, float& ay) {
    for (; p + 15 < end; p += 16) {
        uint4 ea = *(const uint4*)(csr + p);
        uint4 eb = *(const uint4*)(csr + p + 4);
        uint4 ec = *(const uint4*)(csr + p + 8);
        uint4 ed = *(const uint4*)(csr + p + 12);
        __half2 g0 = h2[ea.x + f], g1 = h2[ea.y + f];
        __half2 g2 = h2[ea.z + f], g3 = h2[ea.w + f];
        __half2 g4 = h2[eb.x + f], g5 = h2[eb.y + f];
        __half2 g6 = h2[eb.z + f], g7 = h2[eb.w + f];
        __half2 g8 = h2[ec.x + f], g9 = h2[ec.y + f];
        __half2 ga = h2[ec.z + f], gb = h2[ec.w + f];
        __half2 gc = h2[ed.x + f], gd = h2[ed.y + f];
        __half2 ge = h2[ed.z + f], gf = h2[ed.w + f];
        float2 t0 = __half22float2(__hadd2(g0, g1));
        float2 t1 = __half22float2(__hadd2(g2, g3));
        float2 t2 = __half22float2(__hadd2(g4, g5));
        float2 t3 = __half22float2(__hadd2(g6, g7));
        float2 t4 = __half22float2(__hadd2(g8, g9));
        float2 t5 = __half22float2(__hadd2(ga, gb));
        float2 t6 = __half22float2(__hadd2(gc, gd));
        float2 t7 = __half22float2(__hadd2(ge, gf));
        ax += ((t0.x + t1.x) + (t2.x + t3.x)) + ((t4.x + t5.x) + (t6.x + t7.x));
        ay += ((t0.y + t1.y) + (t2.y + t3.y)) + ((t4.y + t5.y) + (t6.y + t7.y));
    }
    if (p + 7 < end) {
        uint4 ea = *(const uint4*)(csr + p);
        uint4 eb = *(const uint4*)(csr + p + 4);
        __half2 g0 = h2[ea.x + f], g1 = h2[ea.y + f];
        __half2 g2 = h2[ea.z + f], g3 = h2[ea.w + f];
        __half2 g4 = h2[eb.x + f], g5 = h2[eb.y + f];
        __half2 g6 = h2[eb.z + f], g7 = h2[eb.w + f];
        float2 t0 = __half22float2(__hadd2(g0, g1));
        float2 t1 = __half22float2(__hadd2(g2, g3));
        float2 t2 = __half22float2(__hadd2(g4, g5));
        float2 t3 = __half22float2(__hadd2(g6, g7));
        ax += (t0.x + t1.x) + (t2.x + t3.x);
        ay += (t0.y + t1.y) + (t2.y + t3.y);
        p += 8;
    }
    if (p + 3 < end) {
        uint4 e4 = *(const uint4*)(csr + p);
        __half2 g0 = h2[e4.x + f], g1 = h2[e4.y + f];
        __half2 g2 = h2[e4.z + f], g3 = h2[e4.w + f];
        float2 t0 = __half22float2(__hadd2(g0, g1));
        float2 t1 = __half22float2(__hadd2(g2, g3));
        ax += t0.x + t1.x;
        ay += t0.y + t1.y;
        p += 4;
    }
    for (; p < end; ++p) {
        float2 v = __half22float2(h2[csr[p] + f]);
        ax += v.x; ay += v.y;
    }
}

// layer 1: l1 = relu(dinv*(sum + hd[c]) + b1); fused GEMM2 via group shfl
__global__ __launch_bounds__(256) void agg1(const unsigned* __restrict__ csr,
                                            const int* __restrict__ nodeCur,
                                            const __half2* __restrict__ hd,
                                            const float* __restrict__ b1,
                                            const float* __restrict__ W2,
                                            __half2* __restrict__ hd2) {
    __shared__ float sW2[DIM * DIM];
    __shared__ float sb1[DIM];
    const int t = threadIdx.x;
    sW2[t] = W2[t];
    if (t < DIM) sb1[t] = b1[t];
    __syncthreads();
    const int lane = t & 63, f = lane & 7;
    const int node = blockIdx.x * 32 + ((t >> 6) << 3) + (lane >> 3);  // grid exact
    const int degv = nodeCur[node];
    const float dc = rsqrtf((float)degv + 1.0f);
    const int p0 = node * NCAP;
    float ax = 0.f, ay = 0.f;
    node_gather(csr, hd, p0, p0 + degv, f, ax, ay);
    float2 sv = __half22float2(hd[(size_t)node * 8 + f]);
    float fx = dc * (ax + sv.x) + sb1[2 * f];
    float fy = dc * (ay + sv.y) + sb1[2 * f + 1];
    fx = fmaxf(fx, 0.f); fy = fmaxf(fy, 0.f);
    float sx = 0.f, sy = 0.f;
    const int gl = lane & 56;                 // group base lane
#pragma unroll
    for (int mq = 0; mq < 8; ++mq) {
        float lo = __shfl(fx, gl + mq, 64);   // l1[2mq]
        float hi = __shfl(fy, gl + mq, 64);   // l1[2mq+1]
        sx += lo * sW2[(2 * mq) * DIM + 2 * f]     + hi * sW2[(2 * mq + 1) * DIM + 2 * f];
        sy += lo * sW2[(2 * mq) * DIM + 2 * f + 1] + hi * sW2[(2 * mq + 1) * DIM + 2 * f + 1];
    }
    hd2[(size_t)node * 8 + f] = __floats2half2_rn(dc * sx, dc * sy);
}

// layer 2: out = relu(dinv*(sum + hd2[c]) + b2)   (fp32 out)
__global__ __launch_bounds__(256) void agg2(const unsigned* __restrict__ csr,
                                            const int* __restrict__ nodeCur,
                                            const __half2* __restrict__ hd2,
                                            const float* __restrict__ b2,
                                            float2* __restrict__ out2) {
    __shared__ float sb2[DIM];
    const int t = threadIdx.x;
    if (t < DIM) sb2[t] = b2[t];
    __syncthreads();
    const int lane = t & 63, f = lane & 7;
    const int node = blockIdx.x * 32 + ((t >> 6) << 3) + (lane >> 3);
    const int degv = nodeCur[node];
    const float dc = rsqrtf((float)degv + 1.0f);
    const int p0 = node * NCAP;
    float ax = 0.f, ay = 0.f;
    node_gather(csr, hd2, p0, p0 + degv, f, ax, ay);
    float2 sv = __half22float2(hd2[(size_t)node * 8 + f]);
    float fx = dc * (ax + sv.x) + sb2[2 * f];
    float fy = dc * (ay + sv.y) + sb2[2 * f + 1];
    out2[(size_t)node * 8 + f] = make_float2(fmaxf(fx, 0.f), fmaxf(fy, 0.f));
}

extern "C" void kernel_launch(void* const* d_in, const int* in_sizes, int n_in,
                              void* d_out, int out_size, void* d_ws, size_t ws_size,
                              hipStream_t stream) {
    const float* x   = (const float*)d_in[0];
    const int*   ei  = (const int*)d_in[1];        // [2, E] flat: row then col
    const float* W1  = (const float*)d_in[2];
    const float* b1  = (const float*)d_in[3];
    const float* W2  = (const float*)d_in[4];
    const float* b2  = (const float*)d_in[5];
    float*       out = (float*)d_out;

    const int* row = ei;
    const int* col = ei + N_EDGES;

    // workspace (~63 MB of ~268 MB)
    char* ws = (char*)d_ws;
    size_t o = 0;
    auto take = [&](size_t bytes) { char* p = ws + o; o = alignup(o + bytes); return p; };
    int*      nodeCur = (int*)     take((size_t)N_NODES * 4);         // degrees
    int*      cursorA = (int*)     take((size_t)256 * 4);             // rel cursors
    unsigned* stageA  = (unsigned*)take((size_t)NSUP * SCAP * 4);     // 14.0 MB
    unsigned* csr     = (unsigned*)take((size_t)N_NODES * NCAP * 4);  // 38.4 MB
    __half*   hu      = (__half*)  take((size_t)N_NODES * DIM * 2);   // 3.2 MB
    __half*   hd      = (__half*)  take((size_t)N_NODES * DIM * 2);   // 3.2 MB
    __half*   hd2     = (__half*)  take((size_t)N_NODES * DIM * 2);   // 3.2 MB

    // preprocessing + GEMM1 co-scheduled (interleaved block ids)
    zero_init<<<1, 256, 0, stream>>>(cursorA);
    partA_gemm<<<NBLKA + NBLKG, 512, 0, stream>>>(row, col, cursorA, stageA,
                                                  x, W1, hu);
    partB<<<NSUP, 1024, 0, stream>>>(stageA, cursorA, nodeCur, csr,
                                     (const __half2*)hu, (__half2*)hd);

    // network
    agg1<<<N_NODES / 32, 256, 0, stream>>>(csr, nodeCur, (const __half2*)hd,
                                           b1, W2, (__half2*)hd2);
    agg2<<<N_NODES / 32, 256, 0, stream>>>(csr, nodeCur, (const __half2*)hd2,
                                           b2, (float2*)out);
}